// Round 3
// baseline (24608.469 us; speedup 1.0000x reference)
//
#include <hip/hip_runtime.h>
#include <cstddef>
#include <cstdint>

// Problem: GRU  B=32, L=1024, D_IN=512, H=512
// outputs: outs(32,1024,512) then h_last(32,512), flat in d_out.

#define Bsz   32
#define Lsz   1024
#define Hsz   512
#define NG    1536   // 1024 ru gates + 512 cand

// recurrence decomposition
#define NBLK    256   // total blocks (co-resident, cooperative launch)
#define GROUPS  4     // batch groups
#define BPG     64    // blocks (slices) per group
#define BATG    8     // batches per group
#define JB      8     // h-columns owned per block
#define WSTR    516   // row stride: 16B-aligned for ds_read_b128
#define THREADS 256
#define FSTR    16    // flag stride in u32 (64B: one cache line per slice)

typedef float f32x4 __attribute__((ext_vector_type(4)));

__device__ __forceinline__ float sigmoidf_(float v) {
    return 1.0f / (1.0f + __expf(-v));
}
__device__ __forceinline__ float tanhf_(float v) {
    float e = __expf(2.0f * v);           // inf -> 1, 0 -> -1 : correct saturation
    return 1.0f - 2.0f / (e + 1.0f);
}
__device__ __forceinline__ float ld_agent(const float* p) {
    return __hip_atomic_load(p, __ATOMIC_RELAXED, __HIP_MEMORY_SCOPE_AGENT);
}
__device__ __forceinline__ void st_agent(float* p, float v) {
    __hip_atomic_store(p, v, __ATOMIC_RELAXED, __HIP_MEMORY_SCOPE_AGENT);
}
// four coherent 16B loads at +0/+512/+1024/+1536 bytes, single waitcnt.
__device__ __forceinline__ void ld4_agent(const float* p, f32x4& a, f32x4& b,
                                          f32x4& c, f32x4& d) {
    asm volatile(
        "global_load_dwordx4 %0, %4, off sc0 sc1\n\t"
        "global_load_dwordx4 %1, %4, off offset:512 sc0 sc1\n\t"
        "global_load_dwordx4 %2, %4, off offset:1024 sc0 sc1\n\t"
        "global_load_dwordx4 %3, %4, off offset:1536 sc0 sc1\n\t"
        "s_waitcnt vmcnt(0)"
        : "=&v"(a), "=&v"(b), "=&v"(c), "=&v"(d)
        : "v"(p)
        : "memory");
}

// Producer side: all waves' data stores drained by __syncthreads, then one
// RELEASE store of this slice's sequence number.
__device__ __forceinline__ void publish(unsigned* f, int slice, int tid, unsigned v) {
    __syncthreads();
    if (tid == 0)
        __hip_atomic_store(&f[(size_t)slice * FSTR], v,
                           __ATOMIC_RELEASE, __HIP_MEMORY_SCOPE_AGENT);
}
// Consumer side: RELAXED spin (no per-iteration cache invalidate), then ONE
// acquire fence, then workgroup barrier.
__device__ __forceinline__ void wait_ge(const unsigned* f, int tid, unsigned target) {
    if (tid < BPG) {
        while (__hip_atomic_load(&f[(size_t)tid * FSTR], __ATOMIC_RELAXED,
                                 __HIP_MEMORY_SCOPE_AGENT) < target)
            __builtin_amdgcn_s_sleep(1);
    }
    __builtin_amdgcn_fence(__ATOMIC_ACQUIRE, "agent");
    __syncthreads();
}

// Tree-reduce 8 per-lane partials across 32 lanes (lanes l..l^31 share one batch).
// On exit every lane holds, in a[0], the FULL k-sum for column jj = (l & 7).
// (Partition-agnostic: any lane->k assignment works.)
__device__ __forceinline__ void reduce8(float a[8], int l) {
    #pragma unroll
    for (int i = 0; i < 4; ++i) {
        float lo = a[2 * i], hi = a[2 * i + 1];
        float ex = __shfl_xor((l & 1) ? lo : hi, 1);
        a[i] = (l & 1) ? (hi + ex) : (lo + ex);
    }
    #pragma unroll
    for (int i = 0; i < 2; ++i) {
        float lo = a[2 * i], hi = a[2 * i + 1];
        float ex = __shfl_xor((l & 2) ? lo : hi, 2);
        a[i] = (l & 2) ? (hi + ex) : (lo + ex);
    }
    {
        float lo = a[0], hi = a[1];
        float ex = __shfl_xor((l & 4) ? lo : hi, 4);
        a[0] = (l & 4) ? (hi + ex) : (lo + ex);
    }
    a[0] += __shfl_xor(a[0], 8);
    a[0] += __shfl_xor(a[0], 16);
}

__global__ __launch_bounds__(256) void init_h(const float* __restrict__ h0,
                                              float* __restrict__ hstate) {
    int i = blockIdx.x * 256 + threadIdx.x;
    hstate[i] = h0[i];   // parity-0 buffer
}

// ---------------- input-projection GEMM (unchanged) ------------------------
__global__ __launch_bounds__(256) void gemm_pre(const float* __restrict__ x,
                                                const float* __restrict__ W_ru,
                                                const float* __restrict__ b_ru,
                                                const float* __restrict__ W_c,
                                                const float* __restrict__ b_c,
                                                float* __restrict__ pre,
                                                int t0) {
    __shared__ float As[8][128];
    __shared__ float Bs[8][128];
    const int tid = threadIdx.x;
    const int bm = blockIdx.x, bn = blockIdx.y;
    const int tx = tid & 15, ty = tid >> 4;

    const int lrow = tid >> 1;
    const int lk4  = (tid & 1) * 4;
    const int grow = bm * 128 + lrow;          // row = t_local*32 + b
    const int tt = grow >> 5, bb = grow & 31;
    const float* xrow = x + ((size_t)bb * Lsz + (t0 + tt)) * 512;
    const int gn = bn * 128 + lrow;            // output column (gate index)
    const float* wrow = (gn < 1024) ? (W_ru + (size_t)gn * 1024 + 512)
                                    : (W_c  + (size_t)(gn - 1024) * 1024 + 512);

    float acc[8][8];
    #pragma unroll
    for (int i = 0; i < 8; ++i)
        #pragma unroll
        for (int j = 0; j < 8; ++j) acc[i][j] = 0.0f;

    for (int k0 = 0; k0 < 512; k0 += 8) {
        float4 av = *(const float4*)(xrow + k0 + lk4);
        float4 bv = *(const float4*)(wrow + k0 + lk4);
        __syncthreads();
        As[lk4 + 0][lrow] = av.x; As[lk4 + 1][lrow] = av.y;
        As[lk4 + 2][lrow] = av.z; As[lk4 + 3][lrow] = av.w;
        Bs[lk4 + 0][lrow] = bv.x; Bs[lk4 + 1][lrow] = bv.y;
        Bs[lk4 + 2][lrow] = bv.z; Bs[lk4 + 3][lrow] = bv.w;
        __syncthreads();
        #pragma unroll
        for (int k = 0; k < 8; ++k) {
            float a[8], b[8];
            *(float4*)&a[0] = *(const float4*)&As[k][ty * 8];
            *(float4*)&a[4] = *(const float4*)&As[k][ty * 8 + 4];
            *(float4*)&b[0] = *(const float4*)&Bs[k][tx * 8];
            *(float4*)&b[4] = *(const float4*)&Bs[k][tx * 8 + 4];
            #pragma unroll
            for (int i = 0; i < 8; ++i)
                #pragma unroll
                for (int j = 0; j < 8; ++j)
                    acc[i][j] += a[i] * b[j];
        }
    }

    const int row0 = bm * 128 + ty * 8;
    const int col0 = bn * 128 + tx * 8;
    float bias[8];
    #pragma unroll
    for (int j = 0; j < 8; ++j) {
        int c = col0 + j;
        bias[j] = (c < 1024) ? b_ru[c] : b_c[c - 1024];
    }
    #pragma unroll
    for (int i = 0; i < 8; ++i) {
        float4 v0 = make_float4(acc[i][0] + bias[0], acc[i][1] + bias[1],
                                acc[i][2] + bias[2], acc[i][3] + bias[3]);
        float4 v1 = make_float4(acc[i][4] + bias[4], acc[i][5] + bias[5],
                                acc[i][6] + bias[6], acc[i][7] + bias[7]);
        float* p = pre + (size_t)(row0 + i) * NG + col0;
        *(float4*)p = v0;
        *(float4*)(p + 4) = v1;
    }
}

// ---------------- persistent cooperative recurrence ------------------------
// 256 blocks x 256 threads.  group g = bid&3 (XCD-affine), slice = bid>>2
// owns h-columns j0..j0+7 with Wr/Wz/Wc rows LDS-resident (loaded once).
// Producer-consumer sequence flags (fh = h publishes, frh = rh publishes)
// with parity double-buffered h/rh: no full barrier, one one-way propagation
// per phase.  Lane l covers k = kq*128 + l*4 .. +3 (b128-friendly).
__global__ __launch_bounds__(THREADS, 1) void gru_rec(
        const float* __restrict__ W_ru, const float* __restrict__ W_c,
        const float* __restrict__ pre, float* __restrict__ h_buf,
        float* __restrict__ rh_buf, unsigned* __restrict__ flags_all,
        float* __restrict__ out, float* __restrict__ hlast,
        int t0, int Tc) {
    __shared__ float Wl[3 * JB * WSTR];      // 49.5 KB
    float* Wr_s = Wl;
    float* Wz_s = Wl + JB * WSTR;
    float* Wc_s = Wl + 2 * JB * WSTR;

    const int bid   = blockIdx.x;
    const int g     = bid & 3;               // group (spans 2 XCDs under %8 RR)
    const int slice = bid >> 2;              // 0..63 within group
    const int j0    = slice * JB;
    const int tid   = threadIdx.x;
    const int b     = g * BATG + (tid >> 5); // global batch for this thread
    const int l     = tid & 31;
    const int jown  = l & 7;                 // column this lane finalizes
    unsigned* fh  = flags_all + (size_t)g * (2 * BPG * FSTR);
    unsigned* frh = fh + BPG * FSTR;

    // one-time LDS fill: rows j0..j0+7 of Wh_r, Wh_z, Wh_c (k-contiguous)
    for (int idx = tid; idx < JB * 512; idx += THREADS) {
        int jj = idx >> 9, k = idx & 511;
        Wr_s[jj * WSTR + k] = W_ru[(size_t)(j0 + jj) * 1024 + k];
        Wz_s[jj * WSTR + k] = W_ru[(size_t)(512 + j0 + jj) * 1024 + k];
        Wc_s[jj * WSTR + k] = W_c [(size_t)(j0 + jj) * 1024 + k];
    }
    __syncthreads();

    for (int t = 0; t < Tc; ++t) {
        const float* prow = pre + ((size_t)t * Bsz + b) * NG;
        float pg_r = prow[j0 + jown];          // plain loads, no flag dependency
        float pg_z = prow[512 + j0 + jown];
        float pg_c = prow[1024 + j0 + jown];

        // ---- phase A: wait h(t), compute r,z, publish rh(t) ----
        if (t > 0) wait_ge(fh, tid, (unsigned)t);

        const float* hrow = h_buf + ((size_t)(t & 1) * Bsz + b) * Hsz;
        f32x4 hv[4];
        ld4_agent(hrow + l * 4, hv[0], hv[1], hv[2], hv[3]);
        float h_own = ld_agent(hrow + j0 + jown);

        float ar[8], az[8];
        #pragma unroll
        for (int jj = 0; jj < 8; ++jj) { ar[jj] = 0.f; az[jj] = 0.f; }
        #pragma unroll
        for (int kq = 0; kq < 4; ++kq) {
            const f32x4 h4 = hv[kq];
            const int kb = kq * 128 + l * 4;
            #pragma unroll
            for (int jj = 0; jj < 8; ++jj) {
                const f32x4 wr = *(const f32x4*)&Wr_s[jj * WSTR + kb];
                const f32x4 wz = *(const f32x4*)&Wz_s[jj * WSTR + kb];
                ar[jj] += wr.x * h4.x + wr.y * h4.y + wr.z * h4.z + wr.w * h4.w;
                az[jj] += wz.x * h4.x + wz.y * h4.y + wz.z * h4.z + wz.w * h4.w;
            }
        }
        reduce8(ar, l);
        reduce8(az, l);

        float r = sigmoidf_(ar[0] + pg_r);
        float z = sigmoidf_(az[0] + pg_z);
        float* rrow = rh_buf + ((size_t)(t & 1) * Bsz + b) * Hsz;
        if (l < 8) st_agent(rrow + j0 + l, r * h_own);
        publish(frh, slice, tid, (unsigned)(t + 1));

        // ---- phase B: wait rh(t), compute cand + h(t+1), publish ----
        wait_ge(frh, tid, (unsigned)(t + 1));

        f32x4 rv[4];
        ld4_agent(rrow + l * 4, rv[0], rv[1], rv[2], rv[3]);

        float ac[8];
        #pragma unroll
        for (int jj = 0; jj < 8; ++jj) ac[jj] = 0.f;
        #pragma unroll
        for (int kq = 0; kq < 4; ++kq) {
            const f32x4 p4 = rv[kq];
            const int kb = kq * 128 + l * 4;
            #pragma unroll
            for (int jj = 0; jj < 8; ++jj) {
                const f32x4 wc = *(const f32x4*)&Wc_s[jj * WSTR + kb];
                ac[jj] += wc.x * p4.x + wc.y * p4.y + wc.z * p4.z + wc.w * p4.w;
            }
        }
        reduce8(ac, l);

        float c  = tanhf_(ac[0] + pg_c);
        float hn = h_own + z * (c - h_own);      // (1-z)h + z*c
        float* hrow_w = h_buf + ((size_t)((t + 1) & 1) * Bsz + b) * Hsz;
        if (l < 8) {
            st_agent(hrow_w + j0 + l, hn);
            out[((size_t)b * Lsz + (t0 + t)) * Hsz + j0 + l] = hn;
            if (t0 + t == Lsz - 1) hlast[(size_t)b * Hsz + j0 + l] = hn;
        }
        publish(fh, slice, tid, (unsigned)(t + 1));
    }
}

// ---------------------------------------------------------------------------
extern "C" void kernel_launch(void* const* d_in, const int* in_sizes, int n_in,
                              void* d_out, int out_size, void* d_ws, size_t ws_size,
                              hipStream_t stream) {
    const float* x     = (const float*)d_in[0];
    const float* h0    = (const float*)d_in[1];
    const float* W_ru  = (const float*)d_in[2];
    const float* b_ru  = (const float*)d_in[3];
    const float* W_c   = (const float*)d_in[4];
    const float* b_c   = (const float*)d_in[5];
    float* out   = (float*)d_out;
    float* hlast = out + (size_t)Bsz * Lsz * Hsz;

    const int nflags = GROUPS * 2 * BPG * FSTR;   // 8192 u32 = 32 KB

    float* ws       = (float*)d_ws;
    unsigned* flags = (unsigned*)ws;
    float* h_buf    = ws + nflags;                // 2 x 32 x 512 (parity-major)
    float* rh_buf   = h_buf + 2 * Bsz * Hsz;      // 2 x 32 x 512
    float* pre      = rh_buf + 2 * Bsz * Hsz;     // Tc*32*1536

    const size_t fixed_bytes = (size_t)(nflags + 4 * Bsz * Hsz) * 4;
    int Tc = 256;
    while (Tc > 8 && fixed_bytes + (size_t)Tc * Bsz * NG * 4 > ws_size) Tc >>= 1;

    init_h<<<(Bsz * Hsz) / 256, 256, 0, stream>>>(h0, h_buf);

    const int nchunks = Lsz / Tc;
    for (int cidx = 0; cidx < nchunks; ++cidx) {
        int t0 = cidx * Tc;
        gemm_pre<<<dim3((Tc * Bsz) / 128, NG / 128), 256, 0, stream>>>(
            x, W_ru, b_ru, W_c, b_c, pre, t0);
        hipMemsetAsync(flags, 0, nflags * sizeof(unsigned), stream);
        void* args[] = {(void*)&W_ru, (void*)&W_c, (void*)&pre, (void*)&h_buf,
                        (void*)&rh_buf, (void*)&flags, (void*)&out, (void*)&hlast,
                        (void*)&t0, (void*)&Tc};
        hipLaunchCooperativeKernel(reinterpret_cast<void*>(gru_rec),
                                   dim3(NBLK), dim3(THREADS), args, 0u, stream);
    }
}